// Round 10
// baseline (258.144 us; speedup 1.0000x reference)
//
#include <hip/hip_runtime.h>

// TemporalAttention: B=16, T=48, N=256, D=64, H=8, hs=8
// A: per-(b,t,ntile) K/V projections, 8x8 reg tile, W+X in LDS, 128 thr
// B: per-(b,2n) temporal attention, 3 q-rows/thread (99 µs measured)
// W: transpose proj weights into dead v-workspace
// C: proj1(tanh)+proj2, 8x8 reg tile, X + sequential W1/W2 in LDS, 128 thr

#define B_ 16
#define T_ 48
#define N_ 256
#define D_ 64

__device__ __forceinline__ float rcpf(float x) { return __builtin_amdgcn_rcpf(x); }
__device__ __forceinline__ float ex2(float x) { return __builtin_amdgcn_exp2f(x); }
#define LOG2E 1.4426950408889634f

// 8x8 register-tile GEMM step over 4 d's: acc[j][0..7] += X[row_j][d0..d0+3] * W[d][col0..col0+7]
#define GEMM8x8_D4(acc, XLDS, WLDS, d0, rowg, colg)                              \
    {                                                                            \
        float4 xv[8], w0[4], w1[4];                                              \
        _Pragma("unroll")                                                        \
        for (int dd = 0; dd < 4; ++dd) {                                         \
            w0[dd] = *(const float4*)&WLDS[d0 + dd][colg * 8];                   \
            w1[dd] = *(const float4*)&WLDS[d0 + dd][colg * 8 + 4];               \
        }                                                                        \
        _Pragma("unroll")                                                        \
        for (int j = 0; j < 8; ++j) xv[j] = *(const float4*)&XLDS[rowg + 16 * j][d0]; \
        _Pragma("unroll")                                                        \
        for (int j = 0; j < 8; ++j) {                                            \
            acc[j][0] += xv[j].x * w0[0].x + xv[j].y * w0[1].x + xv[j].z * w0[2].x + xv[j].w * w0[3].x; \
            acc[j][1] += xv[j].x * w0[0].y + xv[j].y * w0[1].y + xv[j].z * w0[2].y + xv[j].w * w0[3].y; \
            acc[j][2] += xv[j].x * w0[0].z + xv[j].y * w0[1].z + xv[j].z * w0[2].z + xv[j].w * w0[3].z; \
            acc[j][3] += xv[j].x * w0[0].w + xv[j].y * w0[1].w + xv[j].z * w0[2].w + xv[j].w * w0[3].w; \
            acc[j][4] += xv[j].x * w1[0].x + xv[j].y * w1[1].x + xv[j].z * w1[2].x + xv[j].w * w1[3].x; \
            acc[j][5] += xv[j].x * w1[0].y + xv[j].y * w1[1].y + xv[j].z * w1[2].y + xv[j].w * w1[3].y; \
            acc[j][6] += xv[j].x * w1[0].z + xv[j].y * w1[1].z + xv[j].z * w1[2].z + xv[j].w * w1[3].z; \
            acc[j][7] += xv[j].x * w1[0].w + xv[j].y * w1[1].w + xv[j].z * w1[2].w + xv[j].w * w1[3].w; \
        }                                                                        \
    }

// ---------------------------------------------------------------------------
// Kernel A: k = key @ key_w[b,t] + key_b[b,t]; v likewise.
// grid (768, 2 which, 2 ntile), 128 threads. Thread = 8 rows x 8 cols.
// LDS: X 34.8KB + W 16KB = 50.8KB -> 3 blocks/CU.
// ---------------------------------------------------------------------------
__global__ __launch_bounds__(128) void proj_kv_kernel(
    const float* __restrict__ key, const float* __restrict__ key_w, const float* __restrict__ key_b,
    const float* __restrict__ value, const float* __restrict__ value_w, const float* __restrict__ value_b,
    float* __restrict__ k_out, float* __restrict__ v_out)
{
    const int bt = blockIdx.x;
    const int which = blockIdx.y;
    const int n0 = blockIdx.z * 128;
    const float* __restrict__ in = (which ? value : key) + ((size_t)bt * N_ + n0) * D_;
    const float* __restrict__ w  = (which ? value_w : key_w) + (size_t)bt * D_ * D_;
    const float* __restrict__ bb = (which ? value_b : key_b) + (size_t)bt * D_;
    float* __restrict__ out = (which ? v_out : k_out) + ((size_t)bt * N_ + n0) * D_;

    __shared__ float Xl[128][68];
    __shared__ float Wl[D_][D_];   // [d][e]
    __shared__ float Bl[D_];

    const int tid = threadIdx.x;
    #pragma unroll
    for (int i = tid; i < D_ * D_ / 4; i += 128)
        ((float4*)&Wl[0][0])[i] = ((const float4*)w)[i];
    if (tid < D_) Bl[tid] = bb[tid];
    #pragma unroll
    for (int i = tid; i < 128 * 16; i += 128) {
        const int row = i >> 4, d4 = (i & 15) * 4;
        *(float4*)&Xl[row][d4] = *(const float4*)&in[i * 4];
    }
    __syncthreads();

    const int colg = tid & 7;
    const int rowg = tid >> 3;   // 0..15, rows rowg+16j

    float acc[8][8];
    #pragma unroll
    for (int i = 0; i < 8; ++i) {
        const float bv = Bl[colg * 8 + i];
        #pragma unroll
        for (int j = 0; j < 8; ++j) acc[j][i] = bv;
    }

    #pragma unroll 2
    for (int d0 = 0; d0 < D_; d0 += 4)
        GEMM8x8_D4(acc, Xl, Wl, d0, rowg, colg)

    #pragma unroll
    for (int j = 0; j < 8; ++j) {
        const size_t og = (size_t)(rowg + 16 * j) * D_ + colg * 8;
        *(float4*)&out[og]     = make_float4(acc[j][0], acc[j][1], acc[j][2], acc[j][3]);
        *(float4*)&out[og + 4] = make_float4(acc[j][4], acc[j][5], acc[j][6], acc[j][7]);
    }
}

// ---------------------------------------------------------------------------
// Kernel B: temporal attention (unchanged, 99 µs measured, 78% VALUBusy).
// ---------------------------------------------------------------------------
__global__ __launch_bounds__(256) void attn_kernel(
    const float* __restrict__ query, float* __restrict__ k_xatt, const float* __restrict__ v_in,
    const float* __restrict__ rate)
{
    const int b  = blockIdx.x >> 7;
    const int n0 = (blockIdx.x & 127) * 2;

    __shared__ float K[2][T_][68];
    __shared__ float V[2][T_][68];

    const int tid = threadIdx.x;
    #pragma unroll
    for (int i = tid; i < T_ * 16; i += 256) {
        const int t = i >> 4, d4 = (i & 15) * 4;
        const size_t g0 = ((size_t)(b * T_ + t) * N_ + n0) * D_ + d4;
        *(float4*)&K[0][t][d4] = *(const float4*)&k_xatt[g0];
        *(float4*)&V[0][t][d4] = *(const float4*)&v_in[g0];
        *(float4*)&K[1][t][d4] = *(const float4*)&k_xatt[g0 + D_];
        *(float4*)&V[1][t][d4] = *(const float4*)&v_in[g0 + D_];
    }
    const float rsig = rcpf(1.0f + ex2(-rate[0] * LOG2E));

    const int nl = tid >> 7;
    const int r  = tid & 127;
    const int qg = r >> 3;     // 0..15
    const int h  = r & 7;
    const int n  = n0 + nl;

    const float C1 = 0.35355339059327373f * LOG2E;
    float4 qa[3], qb[3];
    float rdn[3];
    #pragma unroll
    for (int j = 0; j < 3; ++j) {
        const int q = qg + 16 * j;
        const size_t g = ((size_t)(b * T_ + q) * N_ + n) * D_ + h * 8;
        const float4 a = *(const float4*)&query[g];
        const float4 c = *(const float4*)&query[g + 4];
        qa[j] = make_float4(-C1 * a.x, -C1 * a.y, -C1 * a.z, -C1 * a.w);
        qb[j] = make_float4(-C1 * c.x, -C1 * c.y, -C1 * c.z, -C1 * c.w);
        rdn[j] = -rsig * (float)(T_ - q) * LOG2E;
    }
    __syncthreads();

    float4 acc0[3], acc1[3];
    float ssum[3];
    #pragma unroll
    for (int j = 0; j < 3; ++j) {
        acc0[j] = make_float4(0.f, 0.f, 0.f, 0.f);
        acc1[j] = make_float4(0.f, 0.f, 0.f, 0.f);
        ssum[j] = 0.f;
    }

    #pragma unroll 4
    for (int tk = 0; tk < T_; ++tk) {
        const float4 ka = *(const float4*)&K[nl][tk][h * 8];
        const float4 kb = *(const float4*)&K[nl][tk][h * 8 + 4];
        const float4 va = *(const float4*)&V[nl][tk][h * 8];
        const float4 vb = *(const float4*)&V[nl][tk][h * 8 + 4];
        #pragma unroll
        for (int j = 0; j < 3; ++j) {
            const float dn = qa[j].x * ka.x + qa[j].y * ka.y + qa[j].z * ka.z + qa[j].w * ka.w
                           + qb[j].x * kb.x + qb[j].y * kb.y + qb[j].z * kb.z + qb[j].w * kb.w;
            const float E1  = ex2(dn);                 // exp(-sc)
            const float s   = rcpf(1.0f + E1);         // sigmoid(sc)
            const float E2  = ex2(s * rdn[j]);         // exp(-s*rsig*dec)
            const float arg = s * (1.0f + E2) * rcpf(2.0f + E2);
            const float x2  = arg * arg;
            const float th  = arg * (15.0f + x2) * rcpf(15.0f + 6.0f * x2);  // tanh Pade
            const float e   = ex2(th * LOG2E);
            ssum[j] += e;
            acc0[j].x += e * va.x; acc0[j].y += e * va.y; acc0[j].z += e * va.z; acc0[j].w += e * va.w;
            acc1[j].x += e * vb.x; acc1[j].y += e * vb.y; acc1[j].z += e * vb.z; acc1[j].w += e * vb.w;
        }
    }

    #pragma unroll
    for (int j = 0; j < 3; ++j) {
        const float inv = rcpf(ssum[j]);
        const int q = qg + 16 * j;
        const size_t g = ((size_t)(b * T_ + q) * N_ + n) * D_ + h * 8;
        *(float4*)&k_xatt[g]     = make_float4(acc0[j].x * inv, acc0[j].y * inv, acc0[j].z * inv, acc0[j].w * inv);
        *(float4*)&k_xatt[g + 4] = make_float4(acc1[j].x * inv, acc1[j].y * inv, acc1[j].z * inv, acc1[j].w * inv);
    }
}

// ---------------------------------------------------------------------------
// Kernel W: transpose p1w/p2w (64x64) into workspace: wt[d*64+c] = p[c*64+d]
// ---------------------------------------------------------------------------
__global__ __launch_bounds__(256) void wtrans_kernel(
    const float* __restrict__ p1w, const float* __restrict__ p2w,
    float* __restrict__ w1t, float* __restrict__ w2t)
{
    const int i = blockIdx.x * 256 + threadIdx.x;
    if (i < D_ * D_) {
        const int d = i >> 6, c = i & 63;
        w1t[i] = p1w[c * 64 + d];
        w2t[i] = p2w[c * 64 + d];
    }
}

// ---------------------------------------------------------------------------
// Kernel C: out = tanh(x_att @ W1^T + b1) @ W2^T + b2.
// 128 threads, 128 rows/block (1536 blocks). Thread = 8 rows x 8 cols.
// LDS: X 34.8KB + one W buffer 16KB = 50.8KB -> 3 blocks/CU.
// W1 staged first; after proj1 the same buffer is refilled with W2.
// ---------------------------------------------------------------------------
__global__ __launch_bounds__(128) void out_proj_kernel(
    const float* __restrict__ xatt,
    const float* __restrict__ w1t, const float* __restrict__ p1b,
    const float* __restrict__ w2t, const float* __restrict__ p2b,
    float* __restrict__ out)
{
    __shared__ float X[128][68];
    __shared__ float Wl[D_][D_];   // [d][c]

    const int tid = threadIdx.x;
    const size_t m0 = (size_t)blockIdx.x * 128;

    #pragma unroll
    for (int i = tid; i < D_ * D_ / 4; i += 128)
        ((float4*)&Wl[0][0])[i] = ((const float4*)w1t)[i];
    #pragma unroll
    for (int i = tid; i < 128 * 16; i += 128) {
        const int row = i >> 4, d4 = (i & 15) * 4;
        *(float4*)&X[row][d4] = *(const float4*)&xatt[(m0 + row) * D_ + d4];
    }
    __syncthreads();

    const int colg = tid & 7;
    const int rowg = tid >> 3;   // rows rowg+16j

    // ---- proj1 + tanh ----
    float x1[8][8];
    {
        float acc[8][8];
        #pragma unroll
        for (int i = 0; i < 8; ++i) {
            const float bv = p1b[colg * 8 + i];
            #pragma unroll
            for (int j = 0; j < 8; ++j) acc[j][i] = bv;
        }
        #pragma unroll 2
        for (int d0 = 0; d0 < D_; d0 += 4)
            GEMM8x8_D4(acc, X, Wl, d0, rowg, colg)
        #pragma unroll
        for (int j = 0; j < 8; ++j)
            #pragma unroll
            for (int i = 0; i < 8; ++i)
                x1[j][i] = 1.0f - 2.0f * rcpf(ex2(acc[j][i] * (2.0f * LOG2E)) + 1.0f);
    }
    __syncthreads();   // everyone done with X(proj1 input) and W1

    // write x1 back into X; refill Wl with W2
    #pragma unroll
    for (int j = 0; j < 8; ++j) {
        *(float4*)&X[rowg + 16 * j][colg * 8]     = make_float4(x1[j][0], x1[j][1], x1[j][2], x1[j][3]);
        *(float4*)&X[rowg + 16 * j][colg * 8 + 4] = make_float4(x1[j][4], x1[j][5], x1[j][6], x1[j][7]);
    }
    #pragma unroll
    for (int i = tid; i < D_ * D_ / 4; i += 128)
        ((float4*)&Wl[0][0])[i] = ((const float4*)w2t)[i];
    __syncthreads();

    // ---- proj2 ----
    {
        float acc[8][8];
        #pragma unroll
        for (int i = 0; i < 8; ++i) {
            const float bv = p2b[colg * 8 + i];
            #pragma unroll
            for (int j = 0; j < 8; ++j) acc[j][i] = bv;
        }
        #pragma unroll 2
        for (int d0 = 0; d0 < D_; d0 += 4)
            GEMM8x8_D4(acc, X, Wl, d0, rowg, colg)
        #pragma unroll
        for (int j = 0; j < 8; ++j) {
            const size_t og = (m0 + rowg + 16 * j) * D_ + colg * 8;
            *(float4*)&out[og]     = make_float4(acc[j][0], acc[j][1], acc[j][2], acc[j][3]);
            *(float4*)&out[og + 4] = make_float4(acc[j][4], acc[j][5], acc[j][6], acc[j][7]);
        }
    }
}

extern "C" void kernel_launch(void* const* d_in, const int* in_sizes, int n_in,
                              void* d_out, int out_size, void* d_ws, size_t ws_size,
                              hipStream_t stream) {
    const float* query   = (const float*)d_in[0];
    const float* key     = (const float*)d_in[1];
    const float* value   = (const float*)d_in[2];
    const float* key_w   = (const float*)d_in[3];
    const float* key_b   = (const float*)d_in[4];
    const float* value_w = (const float*)d_in[5];
    const float* value_b = (const float*)d_in[6];
    const float* p1w     = (const float*)d_in[7];
    const float* p1b     = (const float*)d_in[8];
    const float* p2w     = (const float*)d_in[9];
    const float* p2b     = (const float*)d_in[10];
    const float* rate    = (const float*)d_in[11];
    float* out = (float*)d_out;

    float* kws = (float*)d_ws;                              // k, then x_att
    float* vws = kws + (size_t)B_ * T_ * N_ * D_;           // v; dead after attn
    float* w1t = vws;                                       // transposed weights
    float* w2t = vws + D_ * D_;                             // (reuse dead v region)

    dim3 gridA(B_ * T_, 2, 2);
    proj_kv_kernel<<<gridA, 128, 0, stream>>>(key, key_w, key_b, value, value_w, value_b, kws, vws);
    attn_kernel<<<B_ * (N_ / 2), 256, 0, stream>>>(query, kws, vws, rate);
    wtrans_kernel<<<16, 256, 0, stream>>>(p1w, p2w, w1t, w2t);
    out_proj_kernel<<<(B_ * T_ * N_) / 128, 128, 0, stream>>>(kws, w1t, p1b, w2t, p2b, out);
}

// Round 11
// 233.057 us; speedup vs baseline: 1.1076x; 1.1076x over previous
//
#include <hip/hip_runtime.h>

// TemporalAttention: B=16, T=48, N=256, D=64, H=8, hs=8
// A: per-(b,t,which,ntile) K/V projection, 256 thr, 4x8 reg tile, b128 X reads
// B: per-(b,2n) temporal attention, 3 q-rows/thread (99 µs measured)
// W: transpose proj weights into dead v-workspace
// C: proj1(tanh)+proj2, 128 thr, 8x8 reg tile, W in LDS (32 µs measured)

#define B_ 16
#define T_ 48
#define N_ 256
#define D_ 64

__device__ __forceinline__ float rcpf(float x) { return __builtin_amdgcn_rcpf(x); }
__device__ __forceinline__ float ex2(float x) { return __builtin_amdgcn_exp2f(x); }
#define LOG2E 1.4426950408889634f

// 8x8 register-tile GEMM step over 4 d's (rows rowg+16j)
#define GEMM8x8_D4(acc, XLDS, WLDS, d0, rowg, colg)                              \
    {                                                                            \
        float4 xv[8], w0[4], w1[4];                                              \
        _Pragma("unroll")                                                        \
        for (int dd = 0; dd < 4; ++dd) {                                         \
            w0[dd] = *(const float4*)&WLDS[d0 + dd][colg * 8];                   \
            w1[dd] = *(const float4*)&WLDS[d0 + dd][colg * 8 + 4];               \
        }                                                                        \
        _Pragma("unroll")                                                        \
        for (int j = 0; j < 8; ++j) xv[j] = *(const float4*)&XLDS[rowg + 16 * j][d0]; \
        _Pragma("unroll")                                                        \
        for (int j = 0; j < 8; ++j) {                                            \
            acc[j][0] += xv[j].x * w0[0].x + xv[j].y * w0[1].x + xv[j].z * w0[2].x + xv[j].w * w0[3].x; \
            acc[j][1] += xv[j].x * w0[0].y + xv[j].y * w0[1].y + xv[j].z * w0[2].y + xv[j].w * w0[3].y; \
            acc[j][2] += xv[j].x * w0[0].z + xv[j].y * w0[1].z + xv[j].z * w0[2].z + xv[j].w * w0[3].z; \
            acc[j][3] += xv[j].x * w0[0].w + xv[j].y * w0[1].w + xv[j].z * w0[2].w + xv[j].w * w0[3].w; \
            acc[j][4] += xv[j].x * w1[0].x + xv[j].y * w1[1].x + xv[j].z * w1[2].x + xv[j].w * w1[3].x; \
            acc[j][5] += xv[j].x * w1[0].y + xv[j].y * w1[1].y + xv[j].z * w1[2].y + xv[j].w * w1[3].y; \
            acc[j][6] += xv[j].x * w1[0].z + xv[j].y * w1[1].z + xv[j].z * w1[2].z + xv[j].w * w1[3].z; \
            acc[j][7] += xv[j].x * w1[0].w + xv[j].y * w1[1].w + xv[j].z * w1[2].w + xv[j].w * w1[3].w; \
        }                                                                        \
    }

// ---------------------------------------------------------------------------
// Kernel A: k = key @ key_w[b,t] + key_b[b,t]; v likewise.
// grid (768, 2 which, 2 ntile), 256 threads (4 waves). Thread = 4 rows x 8 cols
// (rows rowg+32j). LDS: X[128][68] 34.8KB + W 16KB + B = 50.9KB -> 3 blocks/CU
// = 12 waves/CU (stage latency hidden across blocks — round-10's 2-wave
// blocks exposed it: 125 µs, VALUBusy 23%).
// ---------------------------------------------------------------------------
__global__ __launch_bounds__(256) void proj_kv_kernel(
    const float* __restrict__ key, const float* __restrict__ key_w, const float* __restrict__ key_b,
    const float* __restrict__ value, const float* __restrict__ value_w, const float* __restrict__ value_b,
    float* __restrict__ k_out, float* __restrict__ v_out)
{
    const int bt = blockIdx.x;
    const int which = blockIdx.y;
    const int n0 = blockIdx.z * 128;
    const float* __restrict__ in = (which ? value : key) + ((size_t)bt * N_ + n0) * D_;
    const float* __restrict__ w  = (which ? value_w : key_w) + (size_t)bt * D_ * D_;
    const float* __restrict__ bb = (which ? value_b : key_b) + (size_t)bt * D_;
    float* __restrict__ out = (which ? v_out : k_out) + ((size_t)bt * N_ + n0) * D_;

    __shared__ float Xl[128][68];
    __shared__ float Wl[D_][D_];   // [d][e]
    __shared__ float Bl[D_];

    const int tid = threadIdx.x;
    #pragma unroll
    for (int i = tid; i < D_ * D_ / 4; i += 256)
        ((float4*)&Wl[0][0])[i] = ((const float4*)w)[i];
    if (tid < D_) Bl[tid] = bb[tid];
    #pragma unroll
    for (int i = tid; i < 128 * 16; i += 256) {
        const int row = i >> 4, d4 = (i & 15) * 4;
        *(float4*)&Xl[row][d4] = *(const float4*)&in[i * 4];
    }
    __syncthreads();

    const int colg = tid & 7;
    const int rowg = tid >> 3;   // 0..31, rows rowg+32j

    float acc[4][8];
    #pragma unroll
    for (int i = 0; i < 8; ++i) {
        const float bv = Bl[colg * 8 + i];
        #pragma unroll
        for (int j = 0; j < 4; ++j) acc[j][i] = bv;
    }

    #pragma unroll 2
    for (int d0 = 0; d0 < D_; d0 += 4) {
        float4 xv[4], w0[4], w1[4];
        #pragma unroll
        for (int dd = 0; dd < 4; ++dd) {
            w0[dd] = *(const float4*)&Wl[d0 + dd][colg * 8];
            w1[dd] = *(const float4*)&Wl[d0 + dd][colg * 8 + 4];
        }
        #pragma unroll
        for (int j = 0; j < 4; ++j) xv[j] = *(const float4*)&Xl[rowg + 32 * j][d0];
        #pragma unroll
        for (int j = 0; j < 4; ++j) {
            acc[j][0] += xv[j].x * w0[0].x + xv[j].y * w0[1].x + xv[j].z * w0[2].x + xv[j].w * w0[3].x;
            acc[j][1] += xv[j].x * w0[0].y + xv[j].y * w0[1].y + xv[j].z * w0[2].y + xv[j].w * w0[3].y;
            acc[j][2] += xv[j].x * w0[0].z + xv[j].y * w0[1].z + xv[j].z * w0[2].z + xv[j].w * w0[3].z;
            acc[j][3] += xv[j].x * w0[0].w + xv[j].y * w0[1].w + xv[j].z * w0[2].w + xv[j].w * w0[3].w;
            acc[j][4] += xv[j].x * w1[0].x + xv[j].y * w1[1].x + xv[j].z * w1[2].x + xv[j].w * w1[3].x;
            acc[j][5] += xv[j].x * w1[0].y + xv[j].y * w1[1].y + xv[j].z * w1[2].y + xv[j].w * w1[3].y;
            acc[j][6] += xv[j].x * w1[0].z + xv[j].y * w1[1].z + xv[j].z * w1[2].z + xv[j].w * w1[3].z;
            acc[j][7] += xv[j].x * w1[0].w + xv[j].y * w1[1].w + xv[j].z * w1[2].w + xv[j].w * w1[3].w;
        }
    }

    #pragma unroll
    for (int j = 0; j < 4; ++j) {
        const size_t og = (size_t)(rowg + 32 * j) * D_ + colg * 8;
        *(float4*)&out[og]     = make_float4(acc[j][0], acc[j][1], acc[j][2], acc[j][3]);
        *(float4*)&out[og + 4] = make_float4(acc[j][4], acc[j][5], acc[j][6], acc[j][7]);
    }
}

// ---------------------------------------------------------------------------
// Kernel B: temporal attention (unchanged, 99 µs measured, 78% VALUBusy).
// ---------------------------------------------------------------------------
__global__ __launch_bounds__(256) void attn_kernel(
    const float* __restrict__ query, float* __restrict__ k_xatt, const float* __restrict__ v_in,
    const float* __restrict__ rate)
{
    const int b  = blockIdx.x >> 7;
    const int n0 = (blockIdx.x & 127) * 2;

    __shared__ float K[2][T_][68];
    __shared__ float V[2][T_][68];

    const int tid = threadIdx.x;
    #pragma unroll
    for (int i = tid; i < T_ * 16; i += 256) {
        const int t = i >> 4, d4 = (i & 15) * 4;
        const size_t g0 = ((size_t)(b * T_ + t) * N_ + n0) * D_ + d4;
        *(float4*)&K[0][t][d4] = *(const float4*)&k_xatt[g0];
        *(float4*)&V[0][t][d4] = *(const float4*)&v_in[g0];
        *(float4*)&K[1][t][d4] = *(const float4*)&k_xatt[g0 + D_];
        *(float4*)&V[1][t][d4] = *(const float4*)&v_in[g0 + D_];
    }
    const float rsig = rcpf(1.0f + ex2(-rate[0] * LOG2E));

    const int nl = tid >> 7;
    const int r  = tid & 127;
    const int qg = r >> 3;     // 0..15
    const int h  = r & 7;
    const int n  = n0 + nl;

    const float C1 = 0.35355339059327373f * LOG2E;
    float4 qa[3], qb[3];
    float rdn[3];
    #pragma unroll
    for (int j = 0; j < 3; ++j) {
        const int q = qg + 16 * j;
        const size_t g = ((size_t)(b * T_ + q) * N_ + n) * D_ + h * 8;
        const float4 a = *(const float4*)&query[g];
        const float4 c = *(const float4*)&query[g + 4];
        qa[j] = make_float4(-C1 * a.x, -C1 * a.y, -C1 * a.z, -C1 * a.w);
        qb[j] = make_float4(-C1 * c.x, -C1 * c.y, -C1 * c.z, -C1 * c.w);
        rdn[j] = -rsig * (float)(T_ - q) * LOG2E;
    }
    __syncthreads();

    float4 acc0[3], acc1[3];
    float ssum[3];
    #pragma unroll
    for (int j = 0; j < 3; ++j) {
        acc0[j] = make_float4(0.f, 0.f, 0.f, 0.f);
        acc1[j] = make_float4(0.f, 0.f, 0.f, 0.f);
        ssum[j] = 0.f;
    }

    #pragma unroll 4
    for (int tk = 0; tk < T_; ++tk) {
        const float4 ka = *(const float4*)&K[nl][tk][h * 8];
        const float4 kb = *(const float4*)&K[nl][tk][h * 8 + 4];
        const float4 va = *(const float4*)&V[nl][tk][h * 8];
        const float4 vb = *(const float4*)&V[nl][tk][h * 8 + 4];
        #pragma unroll
        for (int j = 0; j < 3; ++j) {
            const float dn = qa[j].x * ka.x + qa[j].y * ka.y + qa[j].z * ka.z + qa[j].w * ka.w
                           + qb[j].x * kb.x + qb[j].y * kb.y + qb[j].z * kb.z + qb[j].w * kb.w;
            const float E1  = ex2(dn);                 // exp(-sc)
            const float s   = rcpf(1.0f + E1);         // sigmoid(sc)
            const float E2  = ex2(s * rdn[j]);         // exp(-s*rsig*dec)
            const float arg = s * (1.0f + E2) * rcpf(2.0f + E2);
            const float x2  = arg * arg;
            const float th  = arg * (15.0f + x2) * rcpf(15.0f + 6.0f * x2);  // tanh Pade
            const float e   = ex2(th * LOG2E);
            ssum[j] += e;
            acc0[j].x += e * va.x; acc0[j].y += e * va.y; acc0[j].z += e * va.z; acc0[j].w += e * va.w;
            acc1[j].x += e * vb.x; acc1[j].y += e * vb.y; acc1[j].z += e * vb.z; acc1[j].w += e * vb.w;
        }
    }

    #pragma unroll
    for (int j = 0; j < 3; ++j) {
        const float inv = rcpf(ssum[j]);
        const int q = qg + 16 * j;
        const size_t g = ((size_t)(b * T_ + q) * N_ + n) * D_ + h * 8;
        *(float4*)&k_xatt[g]     = make_float4(acc0[j].x * inv, acc0[j].y * inv, acc0[j].z * inv, acc0[j].w * inv);
        *(float4*)&k_xatt[g + 4] = make_float4(acc1[j].x * inv, acc1[j].y * inv, acc1[j].z * inv, acc1[j].w * inv);
    }
}

// ---------------------------------------------------------------------------
// Kernel W: transpose p1w/p2w (64x64) into workspace: wt[d*64+c] = p[c*64+d]
// ---------------------------------------------------------------------------
__global__ __launch_bounds__(256) void wtrans_kernel(
    const float* __restrict__ p1w, const float* __restrict__ p2w,
    float* __restrict__ w1t, float* __restrict__ w2t)
{
    const int i = blockIdx.x * 256 + threadIdx.x;
    if (i < D_ * D_) {
        const int d = i >> 6, c = i & 63;
        w1t[i] = p1w[c * 64 + d];
        w2t[i] = p2w[c * 64 + d];
    }
}

// ---------------------------------------------------------------------------
// Kernel C: out = tanh(x_att @ W1^T + b1) @ W2^T + b2. (measured ~32 µs)
// 128 threads, 128 rows/block. Thread = 8 rows x 8 cols. W1 then W2 staged
// into the same LDS buffer. 50.8KB -> 3 blocks/CU.
// ---------------------------------------------------------------------------
__global__ __launch_bounds__(128) void out_proj_kernel(
    const float* __restrict__ xatt,
    const float* __restrict__ w1t, const float* __restrict__ p1b,
    const float* __restrict__ w2t, const float* __restrict__ p2b,
    float* __restrict__ out)
{
    __shared__ float X[128][68];
    __shared__ float Wl[D_][D_];   // [d][c]

    const int tid = threadIdx.x;
    const size_t m0 = (size_t)blockIdx.x * 128;

    #pragma unroll
    for (int i = tid; i < D_ * D_ / 4; i += 128)
        ((float4*)&Wl[0][0])[i] = ((const float4*)w1t)[i];
    #pragma unroll
    for (int i = tid; i < 128 * 16; i += 128) {
        const int row = i >> 4, d4 = (i & 15) * 4;
        *(float4*)&X[row][d4] = *(const float4*)&xatt[(m0 + row) * D_ + d4];
    }
    __syncthreads();

    const int colg = tid & 7;
    const int rowg = tid >> 3;   // rows rowg+16j

    // ---- proj1 + tanh ----
    float x1[8][8];
    {
        float acc[8][8];
        #pragma unroll
        for (int i = 0; i < 8; ++i) {
            const float bv = p1b[colg * 8 + i];
            #pragma unroll
            for (int j = 0; j < 8; ++j) acc[j][i] = bv;
        }
        #pragma unroll 2
        for (int d0 = 0; d0 < D_; d0 += 4)
            GEMM8x8_D4(acc, X, Wl, d0, rowg, colg)
        #pragma unroll
        for (int j = 0; j < 8; ++j)
            #pragma unroll
            for (int i = 0; i < 8; ++i)
                x1[j][i] = 1.0f - 2.0f * rcpf(ex2(acc[j][i] * (2.0f * LOG2E)) + 1.0f);
    }
    __syncthreads();   // everyone done with X(proj1 input) and W1

    // write x1 back into X; refill Wl with W2
    #pragma unroll
    for (int j = 0; j < 8; ++j) {
        *(float4*)&X[rowg + 16 * j][colg * 8]     = make_float4(x1[j][0], x1[j][1], x1[j][2], x1[j][3]);
        *(float4*)&X[rowg + 16 * j][colg * 8 + 4] = make_float4(x1[j][4], x1[j][5], x1[j][6], x1[j][7]);
    }
    #pragma unroll
    for (int i = tid; i < D_ * D_ / 4; i += 128)
        ((float4*)&Wl[0][0])[i] = ((const float4*)w2t)[i];
    __syncthreads();

    // ---- proj2 ----
    {
        float acc[8][8];
        #pragma unroll
        for (int i = 0; i < 8; ++i) {
            const float bv = p2b[colg * 8 + i];
            #pragma unroll
            for (int j = 0; j < 8; ++j) acc[j][i] = bv;
        }
        #pragma unroll 2
        for (int d0 = 0; d0 < D_; d0 += 4)
            GEMM8x8_D4(acc, X, Wl, d0, rowg, colg)
        #pragma unroll
        for (int j = 0; j < 8; ++j) {
            const size_t og = (m0 + rowg + 16 * j) * D_ + colg * 8;
            *(float4*)&out[og]     = make_float4(acc[j][0], acc[j][1], acc[j][2], acc[j][3]);
            *(float4*)&out[og + 4] = make_float4(acc[j][4], acc[j][5], acc[j][6], acc[j][7]);
        }
    }
}

extern "C" void kernel_launch(void* const* d_in, const int* in_sizes, int n_in,
                              void* d_out, int out_size, void* d_ws, size_t ws_size,
                              hipStream_t stream) {
    const float* query   = (const float*)d_in[0];
    const float* key     = (const float*)d_in[1];
    const float* value   = (const float*)d_in[2];
    const float* key_w   = (const float*)d_in[3];
    const float* key_b   = (const float*)d_in[4];
    const float* value_w = (const float*)d_in[5];
    const float* value_b = (const float*)d_in[6];
    const float* p1w     = (const float*)d_in[7];
    const float* p1b     = (const float*)d_in[8];
    const float* p2w     = (const float*)d_in[9];
    const float* p2b     = (const float*)d_in[10];
    const float* rate    = (const float*)d_in[11];
    float* out = (float*)d_out;

    float* kws = (float*)d_ws;                              // k, then x_att
    float* vws = kws + (size_t)B_ * T_ * N_ * D_;           // v; dead after attn
    float* w1t = vws;                                       // transposed weights
    float* w2t = vws + D_ * D_;                             // (reuse dead v region)

    dim3 gridA(B_ * T_, 2, 2);
    proj_kv_kernel<<<gridA, 256, 0, stream>>>(key, key_w, key_b, value, value_w, value_b, kws, vws);
    attn_kernel<<<B_ * (N_ / 2), 256, 0, stream>>>(query, kws, vws, rate);
    wtrans_kernel<<<16, 256, 0, stream>>>(p1w, p2w, w1t, w2t);
    out_proj_kernel<<<(B_ * T_ * N_) / 128, 128, 0, stream>>>(kws, w1t, p1b, w2t, p2b, out);
}